// Round 1
// 543.412 us; speedup vs baseline: 1.0962x; 1.0962x over previous
//
#include <hip/hip_runtime.h>

typedef __attribute__((ext_vector_type(8))) short short8;
typedef __attribute__((ext_vector_type(4))) float f32x4;

#define NB 4
#define NN 512
#define ND 512
#define NH 16
#define NDH 32
#define NPAIR 64

static __device__ __forceinline__ float bf2f(unsigned short u) {
    union { unsigned int i; float f; } x; x.i = ((unsigned int)u) << 16; return x.f;
}
static __device__ __forceinline__ unsigned short f2bf(float f) {
    union { float f; unsigned int i; } x; x.f = f;
    unsigned int i = x.i;
    unsigned int r = (i + 0x7fffu + ((i >> 16) & 1u)) >> 16;
    return (unsigned short)r;
}
static __device__ __forceinline__ short8 cvt8(const float4 lo, const float4 hi) {
    short8 r;
    r[0] = (short)f2bf(lo.x); r[1] = (short)f2bf(lo.y);
    r[2] = (short)f2bf(lo.z); r[3] = (short)f2bf(lo.w);
    r[4] = (short)f2bf(hi.x); r[5] = (short)f2bf(hi.y);
    r[6] = (short)f2bf(hi.z); r[7] = (short)f2bf(hi.w);
    return r;
}

// ---------------------------------------------------------------------------
// K0 prep: split x into hi/lo bf16 planes; transpose+split Wq,Wk,Wv,Wo into
// Wt[n][k] hi/lo bf16 (B-fragment-friendly: lane reads 8 contiguous k).
// grid 320: blocks 0..255 transpose (4 mats x 64 tiles of 64x64), 256..319 x.
// ---------------------------------------------------------------------------
__global__ __launch_bounds__(256) void prep_kernel(
    const float* __restrict__ x, const float* __restrict__ Wq,
    const float* __restrict__ Wk, const float* __restrict__ Wv,
    const float* __restrict__ Wo,
    ushort* __restrict__ x_hi, ushort* __restrict__ x_lo,
    ushort* __restrict__ wt_hi, ushort* __restrict__ wt_lo)
{
    const int tid = threadIdx.x;
    const int bid = blockIdx.x;
    if (bid < 256) {
        __shared__ float ws_[64][65];
        const int mi = bid >> 6;
        const int t = bid & 63;
        const int tr = t >> 3, tc = t & 7;          // k-tile, n-tile
        const float* W = (mi == 0) ? Wq : (mi == 1) ? Wk : (mi == 2) ? Wv : Wo;
        #pragma unroll
        for (int p = 0; p < 4; ++p) {
            const int r = p * 16 + (tid >> 4);      // k within tile
            const int c4 = tid & 15;
            const float4 v = *(const float4*)(W + (size_t)(tr * 64 + r) * 512 + tc * 64 + c4 * 4);
            ws_[r][c4 * 4 + 0] = v.x; ws_[r][c4 * 4 + 1] = v.y;
            ws_[r][c4 * 4 + 2] = v.z; ws_[r][c4 * 4 + 3] = v.w;
        }
        __syncthreads();
        ushort* oh = wt_hi + (size_t)mi * 512 * 512;
        ushort* ol = wt_lo + (size_t)mi * 512 * 512;
        #pragma unroll
        for (int p = 0; p < 4; ++p) {
            const int n = p * 16 + (tid >> 4);      // n within tile
            const int c4 = tid & 15;                // k-group of 4
            const float v0 = ws_[c4 * 4 + 0][n];
            const float v1 = ws_[c4 * 4 + 1][n];
            const float v2 = ws_[c4 * 4 + 2][n];
            const float v3 = ws_[c4 * 4 + 3][n];
            ushort4 h4, l4;
            h4.x = f2bf(v0); l4.x = f2bf(v0 - bf2f(h4.x));
            h4.y = f2bf(v1); l4.y = f2bf(v1 - bf2f(h4.y));
            h4.z = f2bf(v2); l4.z = f2bf(v2 - bf2f(h4.z));
            h4.w = f2bf(v3); l4.w = f2bf(v3 - bf2f(h4.w));
            const size_t o = (size_t)(tc * 64 + n) * 512 + tr * 64 + c4 * 4;
            *(ushort4*)(oh + o) = h4;
            *(ushort4*)(ol + o) = l4;
        }
    } else {
        const int b2 = bid - 256;
        const float4* xg = (const float4*)x;
        for (int i = b2 * 256 + tid; i < (2048 * 512 / 4); i += 64 * 256) {
            const float4 v = xg[i];
            ushort4 h4, l4;
            h4.x = f2bf(v.x); l4.x = f2bf(v.x - bf2f(h4.x));
            h4.y = f2bf(v.y); l4.y = f2bf(v.y - bf2f(h4.y));
            h4.z = f2bf(v.z); l4.z = f2bf(v.z - bf2f(h4.z));
            h4.w = f2bf(v.w); l4.w = f2bf(v.w - bf2f(h4.w));
            *(ushort4*)(x_hi + (size_t)i * 4) = h4;
            *(ushort4*)(x_lo + (size_t)i * 4) = l4;
        }
    }
}

// ---------------------------------------------------------------------------
// K1: QKV via split-bf16 MFMA (Ah*Bh + Ah*Bl + Al*Bh ~= fp32 GEMM).
// grid (8 ntiles, 32 mtiles, 3 which), block 256 = 4 waves; wave = 16m x 64n.
// q,k -> bf16 hi/lo [b,h,n,dh] (A/B-frag friendly); v -> bf16 [b,h,dh,n].
// ---------------------------------------------------------------------------
__global__ __launch_bounds__(256) void qkv_mfma_kernel(
    const ushort* __restrict__ x_hi, const ushort* __restrict__ x_lo,
    const ushort* __restrict__ wt_hi, const ushort* __restrict__ wt_lo,
    ushort* __restrict__ q_hi, ushort* __restrict__ q_lo,
    ushort* __restrict__ k_hi, ushort* __restrict__ k_lo,
    ushort* __restrict__ vT)
{
    const int tid = threadIdx.x, lane = tid & 63, wid = tid >> 6;
    const int c = lane & 15, qd = lane >> 4;
    const int which = blockIdx.z;
    const int m0 = blockIdx.y * 64 + wid * 16;
    const int n0 = blockIdx.x * 64;
    const ushort* wh = wt_hi + (size_t)which * 512 * 512;
    const ushort* wl = wt_lo + (size_t)which * 512 * 512;

    f32x4 z = {0.f, 0.f, 0.f, 0.f};
    f32x4 acc[4];
    #pragma unroll
    for (int nt = 0; nt < 4; ++nt) acc[nt] = z;

    const int arow = m0 + c;
    for (int kc = 0; kc < 512; kc += 32) {
        const short8 ah = *(const short8*)(x_hi + (size_t)arow * 512 + kc + qd * 8);
        const short8 al = *(const short8*)(x_lo + (size_t)arow * 512 + kc + qd * 8);
        #pragma unroll
        for (int nt = 0; nt < 4; ++nt) {
            const int bn = n0 + nt * 16 + c;
            const short8 bh = *(const short8*)(wh + (size_t)bn * 512 + kc + qd * 8);
            const short8 bl = *(const short8*)(wl + (size_t)bn * 512 + kc + qd * 8);
            acc[nt] = __builtin_amdgcn_mfma_f32_16x16x32_bf16(ah, bh, acc[nt], 0, 0, 0);
            acc[nt] = __builtin_amdgcn_mfma_f32_16x16x32_bf16(ah, bl, acc[nt], 0, 0, 0);
            acc[nt] = __builtin_amdgcn_mfma_f32_16x16x32_bf16(al, bh, acc[nt], 0, 0, 0);
        }
    }

    const int bb = m0 >> 9;
    const int nbase = (m0 & 511) + qd * 4;           // D row = qd*4+r (n-seq)
    #pragma unroll
    for (int nt = 0; nt < 4; ++nt) {
        const int col = n0 + nt * 16 + c;            // D col = output feature
        const int h = col >> 5, dh = col & 31;
        if (which == 2) {
            ushort4 o;
            o.x = f2bf(acc[nt][0]); o.y = f2bf(acc[nt][1]);
            o.z = f2bf(acc[nt][2]); o.w = f2bf(acc[nt][3]);
            *(ushort4*)(vT + ((size_t)(bb * 16 + h) * 32 + dh) * 512 + nbase) = o;
        } else {
            ushort* oh = (which == 0) ? q_hi : k_hi;
            ushort* ol = (which == 0) ? q_lo : k_lo;
            #pragma unroll
            for (int r = 0; r < 4; ++r) {
                const size_t ad = ((size_t)(bb * 16 + h) * 512 + nbase + r) * 32 + dh;
                const float v = acc[nt][r];
                const unsigned short hi = f2bf(v);
                oh[ad] = hi;
                ol[ad] = f2bf(v - bf2f(hi));
            }
        }
    }
}

// ---------------------------------------------------------------------------
// K2: bias MFMA (UNCHANGED -- control kernel for the systemic-slowdown probe).
// ---------------------------------------------------------------------------
__global__ __launch_bounds__(256) void bias_kernel(
    const float* __restrict__ pb, const float* __restrict__ Wp,
    ushort* __restrict__ bias_ws)
{
    const int tid = threadIdx.x;
    const int lane = tid & 63, wid = tid >> 6;
    const int col = lane & 15, quad = lane >> 4;

    short8 b0, b1;
    #pragma unroll
    for (int j = 0; j < 8; ++j) {
        b0[j] = (short)f2bf(Wp[(quad * 8 + j) * 16 + col]);
        b1[j] = (short)f2bf(Wp[(32 + quad * 8 + j) * 16 + col]);
    }

    const int gw = blockIdx.x * 4 + wid;
    #pragma unroll
    for (int i = 0; i < 8; ++i) {
        int tile = gw * 8 + i;
        int mt = tile & 31, n = (tile >> 5) & 511, b = tile >> 14;
        int m0 = mt * 16;
        const float* ap = pb + ((size_t)((b * 512 + n) * 512) + m0 + col) * 64 + quad * 8;
        short8 a0 = cvt8(*(const float4*)(ap),      *(const float4*)(ap + 4));
        short8 a1 = cvt8(*(const float4*)(ap + 32), *(const float4*)(ap + 36));
        f32x4 acc = {0.f, 0.f, 0.f, 0.f};
        acc = __builtin_amdgcn_mfma_f32_16x16x32_bf16(a0, b0, acc, 0, 0, 0);
        acc = __builtin_amdgcn_mfma_f32_16x16x32_bf16(a1, b1, acc, 0, 0, 0);
        ushort4 o;
        o.x = f2bf(acc[0]); o.y = f2bf(acc[1]); o.z = f2bf(acc[2]); o.w = f2bf(acc[3]);
        *(ushort4*)(bias_ws + ((size_t)(b * 16 + col) * 512 + n) * 512 + m0 + quad * 4) = o;
    }
}

// ---------------------------------------------------------------------------
// K3: attention, barrier-free. Wave owns 16 query rows x all 512 keys.
// Swapped QK^T: mfma(K, Q) -> lane holds S[m=qd*4+r][n=c]; 128 scores/lane.
// Softmax = lane-local + 2 shfl_xor (lanes n, n+16, n+32, n+48).
// P -> attn (fp32, mandatory) and wave-private LDS (bf16) for on-chip PV.
// grid 1024 x 128 (2 waves/block, fully independent; zero __syncthreads).
// ---------------------------------------------------------------------------
__global__ __launch_bounds__(128) void attn_mfma_kernel(
    const ushort* __restrict__ q_hi, const ushort* __restrict__ q_lo,
    const ushort* __restrict__ k_hi, const ushort* __restrict__ k_lo,
    const ushort* __restrict__ bias_ws, const ushort* __restrict__ vT,
    const int* __restrict__ am, float* __restrict__ attn,
    float* __restrict__ out_ws)
{
    __shared__ __align__(16) ushort Pl[2][16 * 512];   // 32 KB, wave-private halves
    const int tid = threadIdx.x, lane = tid & 63, wid = tid >> 6;
    const int c = lane & 15, qd = lane >> 4;
    const int job = blockIdx.x * 2 + wid;              // 2048 jobs = 64 bh x 32 ntiles
    const int bh = job >> 5, nt = job & 31;
    const int b = bh >> 4, h = bh & 15;
    const int n0 = nt * 16;

    // Q B-fragment (hi/lo), row n = c, k-dim = dh
    const size_t qoff = ((size_t)bh * 512 + n0 + c) * 32 + qd * 8;
    const short8 qbh = *(const short8*)(q_hi + qoff);
    const short8 qbl = *(const short8*)(q_lo + qoff);
    const int rm = am[b * 512 + n0 + c];
    const float scale = 0.17677669529663687f;          // 1/sqrt(32)

    const ushort* khb = k_hi + (size_t)bh * 512 * 32 + qd * 8;
    const ushort* klb = k_lo + (size_t)bh * 512 * 32 + qd * 8;
    const ushort* brow = bias_ws + ((size_t)bh * 512 + n0 + c) * 512 + qd * 4;
    const int* amk = am + b * 512 + qd * 4;

    f32x4 p[32];
    #pragma unroll
    for (int mt = 0; mt < 32; ++mt) {
        const int m0 = mt * 16;
        const short8 kfh = *(const short8*)(khb + (size_t)(m0 + c) * 32);
        const short8 kfl = *(const short8*)(klb + (size_t)(m0 + c) * 32);
        f32x4 a = {0.f, 0.f, 0.f, 0.f};
        a = __builtin_amdgcn_mfma_f32_16x16x32_bf16(kfh, qbh, a, 0, 0, 0);
        a = __builtin_amdgcn_mfma_f32_16x16x32_bf16(kfh, qbl, a, 0, 0, 0);
        a = __builtin_amdgcn_mfma_f32_16x16x32_bf16(kfl, qbh, a, 0, 0, 0);
        const int4    km = *(const int4*)(amk + m0);
        const ushort4 bs = *(const ushort4*)(brow + m0);
        f32x4 o;
        o[0] = km.x ? (a[0] * scale + (rm ? bf2f(bs.x) : 0.f)) : -1e6f;
        o[1] = km.y ? (a[1] * scale + (rm ? bf2f(bs.y) : 0.f)) : -1e6f;
        o[2] = km.z ? (a[2] * scale + (rm ? bf2f(bs.z) : 0.f)) : -1e6f;
        o[3] = km.w ? (a[3] * scale + (rm ? bf2f(bs.w) : 0.f)) : -1e6f;
        p[mt] = o;
    }

    float mx = -3e38f;
    #pragma unroll
    for (int mt = 0; mt < 32; ++mt)
        mx = fmaxf(mx, fmaxf(fmaxf(p[mt][0], p[mt][1]), fmaxf(p[mt][2], p[mt][3])));
    mx = fmaxf(mx, __shfl_xor(mx, 16));
    mx = fmaxf(mx, __shfl_xor(mx, 32));

    float sum = 0.f;
    #pragma unroll
    for (int mt = 0; mt < 32; ++mt) {
        f32x4 e;
        e[0] = __expf(p[mt][0] - mx);
        e[1] = __expf(p[mt][1] - mx);
        e[2] = __expf(p[mt][2] - mx);
        e[3] = __expf(p[mt][3] - mx);
        sum += (e[0] + e[1]) + (e[2] + e[3]);
        p[mt] = e;
    }
    sum += __shfl_xor(sum, 16);
    sum += __shfl_xor(sum, 32);
    const float inv = 1.0f / sum;

    float* arow = attn + ((size_t)bh * 512 + n0 + c) * 512;
    ushort* pl = &Pl[wid][0] + c * 512;                // layout [n=c][m]
    #pragma unroll
    for (int mt = 0; mt < 32; ++mt) {
        f32x4 o;
        o[0] = p[mt][0] * inv; o[1] = p[mt][1] * inv;
        o[2] = p[mt][2] * inv; o[3] = p[mt][3] * inv;
        *(f32x4*)(arow + mt * 16 + qd * 4) = o;        // mandatory attn output
        ushort4 pb4;
        pb4.x = f2bf(o[0]); pb4.y = f2bf(o[1]);
        pb4.z = f2bf(o[2]); pb4.w = f2bf(o[3]);
        *(ushort4*)(pl + mt * 16 + qd * 4) = pb4;      // on-chip P for PV
    }

    // PV: O[dh][n] = sum_m V^T[dh][m] * P[m][n]; A = vT rows (dh), B = P.
    f32x4 oc0 = {0.f, 0.f, 0.f, 0.f}, oc1 = {0.f, 0.f, 0.f, 0.f};
    const ushort* vrow = vT + (size_t)bh * 32 * 512 + qd * 8;
    #pragma unroll
    for (int mc = 0; mc < 16; ++mc) {
        const int m0 = mc * 32;
        const short8 pf = *(const short8*)(pl + m0 + qd * 8);
        const short8 v0 = *(const short8*)(vrow + (size_t)c * 512 + m0);
        const short8 v1 = *(const short8*)(vrow + (size_t)(c + 16) * 512 + m0);
        oc0 = __builtin_amdgcn_mfma_f32_16x16x32_bf16(v0, pf, oc0, 0, 0, 0);
        oc1 = __builtin_amdgcn_mfma_f32_16x16x32_bf16(v1, pf, oc1, 0, 0, 0);
    }
    // D: row = dh (qd*4+r), col = n (c) -> contiguous f32x4 along dh.
    float* op = out_ws + ((size_t)b * 512 + n0 + c) * 512 + h * 32 + qd * 4;
    *(f32x4*)(op) = oc0;
    *(f32x4*)(op + 16) = oc1;
}

// ---------------------------------------------------------------------------
// K4: final = (out @ Wo) * row_mask via split-bf16 MFMA; A split on the fly.
// grid (8, 32), block 256; wave = 16m x 64n.
// ---------------------------------------------------------------------------
__global__ __launch_bounds__(256) void out_mfma_kernel(
    const float* __restrict__ out_in, const ushort* __restrict__ wt_hi,
    const ushort* __restrict__ wt_lo, const int* __restrict__ am,
    float* __restrict__ fin)
{
    const int tid = threadIdx.x, lane = tid & 63, wid = tid >> 6;
    const int c = lane & 15, qd = lane >> 4;
    const int m0 = blockIdx.y * 64 + wid * 16;
    const int n0 = blockIdx.x * 64;
    const ushort* wh = wt_hi + (size_t)3 * 512 * 512;
    const ushort* wl = wt_lo + (size_t)3 * 512 * 512;

    f32x4 z = {0.f, 0.f, 0.f, 0.f};
    f32x4 acc[4];
    #pragma unroll
    for (int nt = 0; nt < 4; ++nt) acc[nt] = z;

    const int arow = m0 + c;
    for (int kc = 0; kc < 512; kc += 32) {
        const float4 xa = *(const float4*)(out_in + (size_t)arow * 512 + kc + qd * 8);
        const float4 xb = *(const float4*)(out_in + (size_t)arow * 512 + kc + qd * 8 + 4);
        short8 ah, al;
        {
            const float vv[8] = {xa.x, xa.y, xa.z, xa.w, xb.x, xb.y, xb.z, xb.w};
            #pragma unroll
            for (int j = 0; j < 8; ++j) {
                const unsigned short hi = f2bf(vv[j]);
                ah[j] = (short)hi;
                al[j] = (short)f2bf(vv[j] - bf2f(hi));
            }
        }
        #pragma unroll
        for (int nt = 0; nt < 4; ++nt) {
            const int bn = n0 + nt * 16 + c;
            const short8 bh = *(const short8*)(wh + (size_t)bn * 512 + kc + qd * 8);
            const short8 bl = *(const short8*)(wl + (size_t)bn * 512 + kc + qd * 8);
            acc[nt] = __builtin_amdgcn_mfma_f32_16x16x32_bf16(ah, bh, acc[nt], 0, 0, 0);
            acc[nt] = __builtin_amdgcn_mfma_f32_16x16x32_bf16(ah, bl, acc[nt], 0, 0, 0);
            acc[nt] = __builtin_amdgcn_mfma_f32_16x16x32_bf16(al, bh, acc[nt], 0, 0, 0);
        }
    }

    const int4 mk = *(const int4*)(am + m0 + qd * 4);
    const float f0 = mk.x ? 1.f : 0.f;
    const float f1 = mk.y ? 1.f : 0.f;
    const float f2 = mk.z ? 1.f : 0.f;
    const float f3 = mk.w ? 1.f : 0.f;
    #pragma unroll
    for (int nt = 0; nt < 4; ++nt) {
        const size_t o = (size_t)(m0 + qd * 4) * 512 + n0 + nt * 16 + c;
        fin[o]        = acc[nt][0] * f0;
        fin[o + 512]  = acc[nt][1] * f1;
        fin[o + 1024] = acc[nt][2] * f2;
        fin[o + 1536] = acc[nt][3] * f3;
    }
}

extern "C" void kernel_launch(void* const* d_in, const int* in_sizes, int n_in,
                              void* d_out, int out_size, void* d_ws, size_t ws_size,
                              hipStream_t stream)
{
    const float* x  = (const float*)d_in[0];
    const float* pb = (const float*)d_in[1];
    const float* Wq = (const float*)d_in[2];
    const float* Wk = (const float*)d_in[3];
    const float* Wv = (const float*)d_in[4];
    const float* Wo = (const float*)d_in[5];
    const float* Wp = (const float*)d_in[6];
    const int*   am = (const int*)d_in[7];

    float* fin  = (float*)d_out;
    float* attn = fin + (size_t)NB * NN * ND;

    char* ws = (char*)d_ws;
    ushort* x_hi    = (ushort*)(ws);                          // 2 MB
    ushort* x_lo    = (ushort*)(ws + 2u  * 1024 * 1024);      // 2 MB
    ushort* wt_hi   = (ushort*)(ws + 4u  * 1024 * 1024);      // 2 MB (4 mats)
    ushort* wt_lo   = (ushort*)(ws + 6u  * 1024 * 1024);      // 2 MB
    ushort* q_hi    = (ushort*)(ws + 8u  * 1024 * 1024);      // 2 MB
    ushort* q_lo    = (ushort*)(ws + 10u * 1024 * 1024);      // 2 MB
    ushort* k_hi    = (ushort*)(ws + 12u * 1024 * 1024);      // 2 MB
    ushort* k_lo    = (ushort*)(ws + 14u * 1024 * 1024);      // 2 MB
    ushort* vT      = (ushort*)(ws + 16u * 1024 * 1024);      // 2 MB
    float*  out_ws  = (float*) (ws + 18u * 1024 * 1024);      // 4 MB
    ushort* bias_ws = (ushort*)(ws + 22u * 1024 * 1024);      // 32 MB

    hipLaunchKernelGGL(prep_kernel, dim3(320), dim3(256), 0, stream,
                       x, Wq, Wk, Wv, Wo, x_hi, x_lo, wt_hi, wt_lo);
    hipLaunchKernelGGL(bias_kernel, dim3(2048), dim3(256), 0, stream,
                       pb, Wp, bias_ws);
    hipLaunchKernelGGL(qkv_mfma_kernel, dim3(8, 32, 3), dim3(256), 0, stream,
                       x_hi, x_lo, wt_hi, wt_lo, q_hi, q_lo, k_hi, k_lo, vT);
    hipLaunchKernelGGL(attn_mfma_kernel, dim3(1024), dim3(128), 0, stream,
                       q_hi, q_lo, k_hi, k_lo, bias_ws, vT, am, attn, out_ws);
    hipLaunchKernelGGL(out_mfma_kernel, dim3(8, 32), dim3(256), 0, stream,
                       out_ws, wt_hi, wt_lo, am, fin);
}